// Round 1
// baseline (10531.207 us; speedup 1.0000x reference)
//
#include <hip/hip_runtime.h>
#include <math.h>

#define N_NODES  100000
#define N_EDGES  6400000
#define N_GRAPHS 1000
#define D_IN  16
#define D_HID 16
#define D_OUT 6

// ---------------------------------------------------------------------------
// Edge kernel: msg = relu(feat[src] + edge_attr[e]); atomicAdd into aggr[dst]
// One thread per edge; edge_attr row read as 4x float4 (64B/thread).
// ---------------------------------------------------------------------------
__global__ __launch_bounds__(256) void edge_kernel(
    const int* __restrict__ ei,      // [2, E]
    const float* __restrict__ feat,  // [N, 16]
    const float* __restrict__ eattr, // [E, 16]
    float* __restrict__ aggr)        // [N, 16] (pre-zeroed)
{
    long e = (long)blockIdx.x * blockDim.x + threadIdx.x;
    if (e >= N_EDGES) return;
    int src = ei[e];
    int dst = ei[N_EDGES + e];
    const float4* a4 = (const float4*)(eattr + e * 16);
    const float4* x4 = (const float4*)(feat + (long)src * 16);
    float* ag = aggr + (long)dst * 16;
#pragma unroll
    for (int q = 0; q < 4; ++q) {
        float4 a = a4[q];
        float4 b = x4[q];
        float m0 = fmaxf(a.x + b.x, 0.0f);
        float m1 = fmaxf(a.y + b.y, 0.0f);
        float m2 = fmaxf(a.z + b.z, 0.0f);
        float m3 = fmaxf(a.w + b.w, 0.0f);
        atomicAdd(ag + q * 4 + 0, m0);
        atomicAdd(ag + q * 4 + 1, m1);
        atomicAdd(ag + q * 4 + 2, m2);
        atomicAdd(ag + q * 4 + 3, m3);
    }
}

// ---------------------------------------------------------------------------
// Node kernel layer 1: h = relu( relu((x+aggr)@W1a + b1a) @ W1b + b1b )
// One thread per node; weights staged in LDS.
// ---------------------------------------------------------------------------
__global__ __launch_bounds__(256) void node1_kernel(
    const float* __restrict__ x, const float* __restrict__ aggr,
    const float* __restrict__ W1a, const float* __restrict__ b1a,
    const float* __restrict__ W1b, const float* __restrict__ b1b,
    float* __restrict__ h)
{
    __shared__ float sWa[256], sWb[256], sba[16], sbb[16];
    int t = threadIdx.x;
    if (t < 256) { sWa[t] = W1a[t]; sWb[t] = W1b[t]; }
    if (t < 16)  { sba[t] = b1a[t]; sbb[t] = b1b[t]; }
    __syncthreads();

    int n = blockIdx.x * blockDim.x + t;
    if (n >= N_NODES) return;

    float v[16];
#pragma unroll
    for (int i = 0; i < 16; ++i) v[i] = x[(long)n * 16 + i] + aggr[(long)n * 16 + i];

    float u[16];
#pragma unroll
    for (int j = 0; j < 16; ++j) {
        float s = sba[j];
#pragma unroll
        for (int i = 0; i < 16; ++i) s += v[i] * sWa[i * 16 + j];
        u[j] = fmaxf(s, 0.0f);
    }
#pragma unroll
    for (int j = 0; j < 16; ++j) {
        float s = sbb[j];
#pragma unroll
        for (int i = 0; i < 16; ++i) s += u[i] * sWb[i * 16 + j];
        h[(long)n * 16 + j] = fmaxf(s, 0.0f);   // outer relu between layers
    }
}

// ---------------------------------------------------------------------------
// Node kernel layer 2: o = relu((h+aggr)@W2a + b2a) @ W2b + b2b  -> [N, 6]
// then atomic pool: sums[batch[n]] += o ; counts[batch[n]] += 1
// ---------------------------------------------------------------------------
__global__ __launch_bounds__(256) void node2_kernel(
    const float* __restrict__ h, const float* __restrict__ aggr,
    const int* __restrict__ batch,
    const float* __restrict__ W2a, const float* __restrict__ b2a,
    const float* __restrict__ W2b, const float* __restrict__ b2b,
    float* __restrict__ sums, float* __restrict__ counts)
{
    __shared__ float sWa[16 * 6], sWb[6 * 6], sba[6], sbb[6];
    int t = threadIdx.x;
    if (t < 96) sWa[t] = W2a[t];
    if (t < 36) sWb[t] = W2b[t];
    if (t < 6)  { sba[t] = b2a[t]; sbb[t] = b2b[t]; }
    __syncthreads();

    int n = blockIdx.x * blockDim.x + t;
    if (n >= N_NODES) return;

    float v[16];
#pragma unroll
    for (int i = 0; i < 16; ++i) v[i] = h[(long)n * 16 + i] + aggr[(long)n * 16 + i];

    float u[6];
#pragma unroll
    for (int j = 0; j < 6; ++j) {
        float s = sba[j];
#pragma unroll
        for (int i = 0; i < 16; ++i) s += v[i] * sWa[i * 6 + j];
        u[j] = fmaxf(s, 0.0f);
    }
    int g = batch[n];
#pragma unroll
    for (int j = 0; j < 6; ++j) {
        float s = sbb[j];
#pragma unroll
        for (int i = 0; i < 6; ++i) s += u[i] * sWb[i * 6 + j];
        atomicAdd(&sums[(long)g * 6 + j], s);
    }
    atomicAdd(&counts[g], 1.0f);
}

// ---------------------------------------------------------------------------
// Pool kernel: pooled = sums/max(counts,1); out = log_softmax(pooled, axis=1)
// ---------------------------------------------------------------------------
__global__ __launch_bounds__(256) void pool_kernel(
    const float* __restrict__ sums, const float* __restrict__ counts,
    float* __restrict__ out)
{
    int g = blockIdx.x * blockDim.x + threadIdx.x;
    if (g >= N_GRAPHS) return;
    float c = fmaxf(counts[g], 1.0f);
    float p[6];
    float mx = -INFINITY;
#pragma unroll
    for (int j = 0; j < 6; ++j) {
        p[j] = sums[(long)g * 6 + j] / c;
        mx = fmaxf(mx, p[j]);
    }
    float se = 0.0f;
#pragma unroll
    for (int j = 0; j < 6; ++j) se += expf(p[j] - mx);
    float lse = mx + logf(se);
#pragma unroll
    for (int j = 0; j < 6; ++j) out[(long)g * 6 + j] = p[j] - lse;
}

// ---------------------------------------------------------------------------
extern "C" void kernel_launch(void* const* d_in, const int* in_sizes, int n_in,
                              void* d_out, int out_size, void* d_ws, size_t ws_size,
                              hipStream_t stream)
{
    const float* x     = (const float*)d_in[0];
    const int*   ei    = (const int*)  d_in[1];   // [2, E] int32 (JAX x64 disabled)
    const float* eattr = (const float*)d_in[2];
    const int*   batch = (const int*)  d_in[3];
    const float* W1a = (const float*)d_in[4];
    const float* b1a = (const float*)d_in[5];
    const float* W1b = (const float*)d_in[6];
    const float* b1b = (const float*)d_in[7];
    const float* W2a = (const float*)d_in[8];
    const float* b2a = (const float*)d_in[9];
    const float* W2b = (const float*)d_in[10];
    const float* b2b = (const float*)d_in[11];
    float* out = (float*)d_out;

    // workspace layout
    float* aggr   = (float*)d_ws;                    // [N,16]  6.4 MB (reused both layers)
    float* h      = aggr + (size_t)N_NODES * 16;     // [N,16]  6.4 MB
    float* sums   = h    + (size_t)N_NODES * 16;     // [G,6]   24 KB
    float* counts = sums + (size_t)N_GRAPHS * 6;     // [G]      4 KB

    const int TB = 256;
    const int edge_blocks = (N_EDGES + TB - 1) / TB;
    const int node_blocks = (N_NODES + TB - 1) / TB;

    // ---- layer 1 ----
    hipMemsetAsync(aggr, 0, (size_t)N_NODES * 16 * sizeof(float), stream);
    edge_kernel<<<edge_blocks, TB, 0, stream>>>(ei, x, eattr, aggr);
    node1_kernel<<<node_blocks, TB, 0, stream>>>(x, aggr, W1a, b1a, W1b, b1b, h);

    // ---- layer 2 ----
    hipMemsetAsync(aggr, 0, (size_t)N_NODES * 16 * sizeof(float), stream);
    hipMemsetAsync(sums, 0, (size_t)(N_GRAPHS * 6 + N_GRAPHS) * sizeof(float), stream);
    edge_kernel<<<edge_blocks, TB, 0, stream>>>(ei, h, eattr, aggr);
    node2_kernel<<<node_blocks, TB, 0, stream>>>(h, aggr, batch, W2a, b2a, W2b, b2b,
                                                 sums, counts);

    // ---- pool + log_softmax ----
    pool_kernel<<<(N_GRAPHS + TB - 1) / TB, TB, 0, stream>>>(sums, counts, out);
}

// Round 2
// 1536.833 us; speedup vs baseline: 6.8525x; 6.8525x over previous
//
#include <hip/hip_runtime.h>
#include <math.h>

#define N_NODES  100000
#define N_EDGES  6400000
#define N_GRAPHS 1000
#define D_IN  16
#define D_HID 16
#define D_OUT 6

// ---------------------------------------------------------------------------
// CSR build step 1: histogram of dst
// ---------------------------------------------------------------------------
__global__ __launch_bounds__(256) void hist_kernel(
    const int* __restrict__ ei, int* __restrict__ cnt)
{
    int e = blockIdx.x * blockDim.x + threadIdx.x;
    if (e >= N_EDGES) return;
    atomicAdd(&cnt[ei[N_EDGES + e]], 1);
}

// ---------------------------------------------------------------------------
// CSR build step 2: exclusive scan over cnt[N_NODES] -> offs[N_NODES+1]
// Single workgroup of 1024, sequential 1024-chunks with LDS Hillis-Steele.
// ---------------------------------------------------------------------------
__global__ __launch_bounds__(1024) void scan_kernel(
    const int* __restrict__ cnt, int* __restrict__ offs)
{
    __shared__ int buf[1024];
    __shared__ int carry_s;
    int t = threadIdx.x;
    if (t == 0) carry_s = 0;
    __syncthreads();
    for (int base = 0; base < N_NODES; base += 1024) {
        int idx = base + t;
        int v = (idx < N_NODES) ? cnt[idx] : 0;
        buf[t] = v;
        __syncthreads();
        for (int d = 1; d < 1024; d <<= 1) {
            int add = (t >= d) ? buf[t - d] : 0;
            __syncthreads();
            buf[t] += add;
            __syncthreads();
        }
        int carry = carry_s;
        if (idx < N_NODES) offs[idx] = carry + buf[t] - v;   // exclusive
        __syncthreads();                  // all lanes read carry_s first
        if (t == 1023) carry_s = carry + buf[1023];
        __syncthreads();
    }
    if (t == 0) offs[N_NODES] = carry_s;
}

// ---------------------------------------------------------------------------
// CSR build step 3: place (src, edge_id) pairs; cursor starts as offs copy
// ---------------------------------------------------------------------------
__global__ __launch_bounds__(256) void place_kernel(
    const int* __restrict__ ei, int* __restrict__ cursor, int2* __restrict__ csr)
{
    int e = blockIdx.x * blockDim.x + threadIdx.x;
    if (e >= N_EDGES) return;
    int src = ei[e];
    int dst = ei[N_EDGES + e];
    int pos = atomicAdd(&cursor[dst], 1);
    csr[pos] = make_int2(src, e);
}

// ---------------------------------------------------------------------------
// Gather: 16 lanes per node (lane = feature channel).
// aggr[n][j] = sum_e relu(feat[src(e)][j] + eattr[e][j])   -- no atomics
// ---------------------------------------------------------------------------
__global__ __launch_bounds__(256) void gather_kernel(
    const int* __restrict__ offs, const int2* __restrict__ csr,
    const float* __restrict__ feat, const float* __restrict__ eattr,
    float* __restrict__ aggr)
{
    int t = threadIdx.x;
    int lane = t & 15;
    int n = blockIdx.x * 16 + (t >> 4);
    if (n >= N_NODES) return;
    int beg = offs[n], end = offs[n + 1];
    float acc = 0.0f;
    int i = beg;
    for (; i + 4 <= end; i += 4) {
        int2 p0 = csr[i + 0];
        int2 p1 = csr[i + 1];
        int2 p2 = csr[i + 2];
        int2 p3 = csr[i + 3];
        float a0 = eattr[p0.y * 16 + lane] + feat[p0.x * 16 + lane];
        float a1 = eattr[p1.y * 16 + lane] + feat[p1.x * 16 + lane];
        float a2 = eattr[p2.y * 16 + lane] + feat[p2.x * 16 + lane];
        float a3 = eattr[p3.y * 16 + lane] + feat[p3.x * 16 + lane];
        acc += fmaxf(a0, 0.0f) + fmaxf(a1, 0.0f)
             + fmaxf(a2, 0.0f) + fmaxf(a3, 0.0f);
    }
    for (; i < end; ++i) {
        int2 p = csr[i];
        acc += fmaxf(eattr[p.y * 16 + lane] + feat[p.x * 16 + lane], 0.0f);
    }
    aggr[n * 16 + lane] = acc;
}

// ---------------------------------------------------------------------------
// Node kernel layer 1: h = relu( relu((x+aggr)@W1a + b1a) @ W1b + b1b )
// ---------------------------------------------------------------------------
__global__ __launch_bounds__(256) void node1_kernel(
    const float* __restrict__ x, const float* __restrict__ aggr,
    const float* __restrict__ W1a, const float* __restrict__ b1a,
    const float* __restrict__ W1b, const float* __restrict__ b1b,
    float* __restrict__ h)
{
    __shared__ float sWa[256], sWb[256], sba[16], sbb[16];
    int t = threadIdx.x;
    if (t < 256) { sWa[t] = W1a[t]; sWb[t] = W1b[t]; }
    if (t < 16)  { sba[t] = b1a[t]; sbb[t] = b1b[t]; }
    __syncthreads();

    int n = blockIdx.x * blockDim.x + t;
    if (n >= N_NODES) return;

    float v[16];
#pragma unroll
    for (int i = 0; i < 16; ++i) v[i] = x[n * 16 + i] + aggr[n * 16 + i];

    float u[16];
#pragma unroll
    for (int j = 0; j < 16; ++j) {
        float s = sba[j];
#pragma unroll
        for (int i = 0; i < 16; ++i) s += v[i] * sWa[i * 16 + j];
        u[j] = fmaxf(s, 0.0f);
    }
#pragma unroll
    for (int j = 0; j < 16; ++j) {
        float s = sbb[j];
#pragma unroll
        for (int i = 0; i < 16; ++i) s += u[i] * sWb[i * 16 + j];
        h[n * 16 + j] = fmaxf(s, 0.0f);   // outer relu between layers
    }
}

// ---------------------------------------------------------------------------
// Node kernel layer 2 + pooling accumulation
// ---------------------------------------------------------------------------
__global__ __launch_bounds__(256) void node2_kernel(
    const float* __restrict__ h, const float* __restrict__ aggr,
    const int* __restrict__ batch,
    const float* __restrict__ W2a, const float* __restrict__ b2a,
    const float* __restrict__ W2b, const float* __restrict__ b2b,
    float* __restrict__ sums, float* __restrict__ counts)
{
    __shared__ float sWa[16 * 6], sWb[6 * 6], sba[6], sbb[6];
    int t = threadIdx.x;
    if (t < 96) sWa[t] = W2a[t];
    if (t < 36) sWb[t] = W2b[t];
    if (t < 6)  { sba[t] = b2a[t]; sbb[t] = b2b[t]; }
    __syncthreads();

    int n = blockIdx.x * blockDim.x + t;
    if (n >= N_NODES) return;

    float v[16];
#pragma unroll
    for (int i = 0; i < 16; ++i) v[i] = h[n * 16 + i] + aggr[n * 16 + i];

    float u[6];
#pragma unroll
    for (int j = 0; j < 6; ++j) {
        float s = sba[j];
#pragma unroll
        for (int i = 0; i < 16; ++i) s += v[i] * sWa[i * 6 + j];
        u[j] = fmaxf(s, 0.0f);
    }
    int g = batch[n];
#pragma unroll
    for (int j = 0; j < 6; ++j) {
        float s = sbb[j];
#pragma unroll
        for (int i = 0; i < 6; ++i) s += u[i] * sWb[i * 6 + j];
        atomicAdd(&sums[g * 6 + j], s);
    }
    atomicAdd(&counts[g], 1.0f);
}

// ---------------------------------------------------------------------------
// Pool + log_softmax
// ---------------------------------------------------------------------------
__global__ __launch_bounds__(256) void pool_kernel(
    const float* __restrict__ sums, const float* __restrict__ counts,
    float* __restrict__ out)
{
    int g = blockIdx.x * blockDim.x + threadIdx.x;
    if (g >= N_GRAPHS) return;
    float c = fmaxf(counts[g], 1.0f);
    float p[6];
    float mx = -INFINITY;
#pragma unroll
    for (int j = 0; j < 6; ++j) {
        p[j] = sums[g * 6 + j] / c;
        mx = fmaxf(mx, p[j]);
    }
    float se = 0.0f;
#pragma unroll
    for (int j = 0; j < 6; ++j) se += expf(p[j] - mx);
    float lse = mx + logf(se);
#pragma unroll
    for (int j = 0; j < 6; ++j) out[g * 6 + j] = p[j] - lse;
}

// ---------------------------------------------------------------------------
extern "C" void kernel_launch(void* const* d_in, const int* in_sizes, int n_in,
                              void* d_out, int out_size, void* d_ws, size_t ws_size,
                              hipStream_t stream)
{
    const float* x     = (const float*)d_in[0];
    const int*   ei    = (const int*)  d_in[1];   // [2, E] int32
    const float* eattr = (const float*)d_in[2];
    const int*   batch = (const int*)  d_in[3];
    const float* W1a = (const float*)d_in[4];
    const float* b1a = (const float*)d_in[5];
    const float* W1b = (const float*)d_in[6];
    const float* b1b = (const float*)d_in[7];
    const float* W2a = (const float*)d_in[8];
    const float* b2a = (const float*)d_in[9];
    const float* W2b = (const float*)d_in[10];
    const float* b2b = (const float*)d_in[11];
    float* out = (float*)d_out;

    // workspace layout (~64.9 MB)
    int2*  csr    = (int2*)d_ws;                         // [E]      51.2 MB
    float* aggr   = (float*)(csr + (size_t)N_EDGES);     // [N,16]    6.4 MB
    float* h      = aggr + (size_t)N_NODES * 16;         // [N,16]    6.4 MB
    int*   cnt    = (int*)(h + (size_t)N_NODES * 16);    // [N]       0.4 MB (also cursor)
    int*   offs   = cnt + N_NODES;                       // [N+1]     0.4 MB
    float* sums   = (float*)(offs + N_NODES + 1);        // [G,6]
    float* counts = sums + (size_t)N_GRAPHS * 6;         // [G]

    const int TB = 256;
    const int edge_blocks = (N_EDGES + TB - 1) / TB;
    const int node_blocks = (N_NODES + TB - 1) / TB;
    const int gather_blocks = (N_NODES + 15) / 16;       // 16 nodes/block

    // ---- CSR build (shared by both layers) ----
    hipMemsetAsync(cnt, 0, (size_t)N_NODES * sizeof(int), stream);
    hist_kernel<<<edge_blocks, TB, 0, stream>>>(ei, cnt);
    scan_kernel<<<1, 1024, 0, stream>>>(cnt, offs);
    hipMemcpyAsync(cnt, offs, (size_t)N_NODES * sizeof(int),
                   hipMemcpyDeviceToDevice, stream);     // cursor = offs
    place_kernel<<<edge_blocks, TB, 0, stream>>>(ei, cnt, csr);

    // ---- layer 1 ----
    gather_kernel<<<gather_blocks, TB, 0, stream>>>(offs, csr, x, eattr, aggr);
    node1_kernel<<<node_blocks, TB, 0, stream>>>(x, aggr, W1a, b1a, W1b, b1b, h);

    // ---- layer 2 ----
    gather_kernel<<<gather_blocks, TB, 0, stream>>>(offs, csr, h, eattr, aggr);
    hipMemsetAsync(sums, 0, (size_t)(N_GRAPHS * 6 + N_GRAPHS) * sizeof(float), stream);
    node2_kernel<<<node_blocks, TB, 0, stream>>>(h, aggr, batch, W2a, b2a, W2b, b2b,
                                                 sums, counts);

    // ---- pool + log_softmax ----
    pool_kernel<<<(N_GRAPHS + TB - 1) / TB, TB, 0, stream>>>(sums, counts, out);
}

// Round 3
// 661.540 us; speedup vs baseline: 15.9192x; 2.3231x over previous
//
#include <hip/hip_runtime.h>
#include <math.h>

#define N_NODES  100000
#define N_EDGES  6400000
#define N_GRAPHS 1000
#define D_IN  16
#define D_HID 16
#define D_OUT 6

#define B_NODES   64                               // nodes per bucket
#define NBUCK     ((N_NODES + B_NODES - 1) / B_NODES)   // 1563
#define EPB       16384                            // edges per block (K1/K3)
#define KBLOCKS   ((N_EDGES + EPB - 1) / EPB)      // 391
#define CAP       6144                             // max edges/bucket staged in LDS

// ---------------------------------------------------------------------------
// K1: per-block LDS histogram of dst buckets -> global bucket counts
// ---------------------------------------------------------------------------
__global__ __launch_bounds__(1024) void count_buckets(
    const int* __restrict__ ei, int* __restrict__ gcnt)
{
    __shared__ int hist[NBUCK];
    int t = threadIdx.x;
    for (int i = t; i < NBUCK; i += 1024) hist[i] = 0;
    __syncthreads();
    int e0 = blockIdx.x * EPB;
#pragma unroll
    for (int k = 0; k < EPB / 1024; ++k) {
        int e = e0 + k * 1024 + t;
        if (e < N_EDGES) atomicAdd(&hist[ei[N_EDGES + e] >> 6], 1);
    }
    __syncthreads();
    for (int i = t; i < NBUCK; i += 1024) {
        int h = hist[i];
        if (h) atomicAdd(&gcnt[i], h);
    }
}

// ---------------------------------------------------------------------------
// K2: exclusive scan of bucket counts (1563) -> base, cursor; sentinels
// ---------------------------------------------------------------------------
__global__ __launch_bounds__(1024) void scan_buckets(
    const int* __restrict__ gcnt, int* __restrict__ base,
    int* __restrict__ cursor, int* __restrict__ offs)
{
    __shared__ int wsum[16];
    int t = threadIdx.x, lane = t & 63, wave = t >> 6;
    int v0 = (2 * t     < NBUCK) ? gcnt[2 * t]     : 0;
    int v1 = (2 * t + 1 < NBUCK) ? gcnt[2 * t + 1] : 0;
    int s = v0 + v1, sc = s;
#pragma unroll
    for (int d = 1; d < 64; d <<= 1) {
        int o = __shfl_up(sc, d, 64);
        if (lane >= d) sc += o;
    }
    if (lane == 63) wsum[wave] = sc;
    __syncthreads();
    if (t < 16) {
        int w = wsum[t];
#pragma unroll
        for (int d = 1; d < 16; d <<= 1) {
            int o = __shfl_up(w, d, 16);
            if (t >= d) w += o;
        }
        wsum[t] = w;
    }
    __syncthreads();
    int wbase = wave ? wsum[wave - 1] : 0;
    int excl = wbase + sc - s;
    if (2 * t < NBUCK)     { base[2 * t]     = excl;      cursor[2 * t]     = excl; }
    if (2 * t + 1 < NBUCK) { base[2 * t + 1] = excl + v0; cursor[2 * t + 1] = excl + v0; }
    if (t == 0) { base[NBUCK] = N_EDGES; offs[N_NODES] = N_EDGES; }
}

// ---------------------------------------------------------------------------
// K3: scatter edges into bucket-clustered tmp. payload: {(dstLow<<23)|e, src}
// Per-block LDS hist -> one global cursor atomic per (block,bucket).
// ---------------------------------------------------------------------------
__global__ __launch_bounds__(1024) void scatter_buckets(
    const int* __restrict__ ei, int* __restrict__ cursor, int2* __restrict__ tmp)
{
    __shared__ int hist[NBUCK];   // counts, then local rank cursors
    __shared__ int base[NBUCK];   // this block's reserved base per bucket
    int t = threadIdx.x;
    for (int i = t; i < NBUCK; i += 1024) hist[i] = 0;
    __syncthreads();
    int e0 = blockIdx.x * EPB;
#pragma unroll
    for (int k = 0; k < EPB / 1024; ++k) {
        int e = e0 + k * 1024 + t;
        if (e < N_EDGES) atomicAdd(&hist[ei[N_EDGES + e] >> 6], 1);
    }
    __syncthreads();
    for (int i = t; i < NBUCK; i += 1024) {
        int h = hist[i];
        base[i] = h ? atomicAdd(&cursor[i], h) : 0;
        hist[i] = 0;              // becomes local rank cursor
    }
    __syncthreads();
#pragma unroll
    for (int k = 0; k < EPB / 1024; ++k) {
        int e = e0 + k * 1024 + t;
        if (e < N_EDGES) {
            int dst = ei[N_EDGES + e];
            int src = ei[e];
            int b = dst >> 6;
            int r = atomicAdd(&hist[b], 1);
            tmp[base[b] + r] = make_int2(((dst & 63) << 23) | e, src);
        }
    }
}

// ---------------------------------------------------------------------------
// K4: per-bucket counting sort in LDS -> final CSR {src, e} + offs
// ---------------------------------------------------------------------------
__global__ __launch_bounds__(1024) void bucket_place(
    const int* __restrict__ base, const int2* __restrict__ tmp,
    int2* __restrict__ csr, int* __restrict__ offs)
{
    __shared__ int2 stage[CAP];
    __shared__ int hist[B_NODES];
    int b = blockIdx.x, t = threadIdx.x;
    int beg = base[b], end = base[b + 1];
    int m = end - beg;
    if (m > CAP) m = CAP;         // safety clamp (never expected to trigger)
    for (int i = t; i < m; i += 1024) stage[i] = tmp[beg + i];
    if (t < B_NODES) hist[t] = 0;
    __syncthreads();
    for (int i = t; i < m; i += 1024)
        atomicAdd(&hist[(stage[i].x >> 23) & 63], 1);
    __syncthreads();
    if (t < 64) {
        int v = hist[t], sc = v;
#pragma unroll
        for (int d = 1; d < 64; d <<= 1) {
            int o = __shfl_up(sc, d, 64);
            if (t >= d) sc += o;
        }
        int ex = sc - v;
        int node = b * 64 + t;
        if (node < N_NODES) offs[node] = beg + ex;
        hist[t] = ex;             // becomes scatter cursor
    }
    __syncthreads();
    for (int i = t; i < m; i += 1024) {
        int2 p = stage[i];
        int dlow = (p.x >> 23) & 63;
        int e = p.x & 0x7FFFFF;
        int r = atomicAdd(&hist[dlow], 1);
        csr[beg + r] = make_int2(p.y, e);   // {src, e}
    }
}

// ---------------------------------------------------------------------------
// Gather: 16 lanes per node (lane = feature channel), no atomics.
// ---------------------------------------------------------------------------
__global__ __launch_bounds__(256) void gather_kernel(
    const int* __restrict__ offs, const int2* __restrict__ csr,
    const float* __restrict__ feat, const float* __restrict__ eattr,
    float* __restrict__ aggr)
{
    int t = threadIdx.x;
    int lane = t & 15;
    int n = blockIdx.x * 16 + (t >> 4);
    if (n >= N_NODES) return;
    int beg = offs[n], end = offs[n + 1];
    float acc = 0.0f;
    int i = beg;
    for (; i + 4 <= end; i += 4) {
        int2 p0 = csr[i + 0];
        int2 p1 = csr[i + 1];
        int2 p2 = csr[i + 2];
        int2 p3 = csr[i + 3];
        float a0 = __builtin_nontemporal_load(eattr + p0.y * 16 + lane) + feat[p0.x * 16 + lane];
        float a1 = __builtin_nontemporal_load(eattr + p1.y * 16 + lane) + feat[p1.x * 16 + lane];
        float a2 = __builtin_nontemporal_load(eattr + p2.y * 16 + lane) + feat[p2.x * 16 + lane];
        float a3 = __builtin_nontemporal_load(eattr + p3.y * 16 + lane) + feat[p3.x * 16 + lane];
        acc += fmaxf(a0, 0.0f) + fmaxf(a1, 0.0f)
             + fmaxf(a2, 0.0f) + fmaxf(a3, 0.0f);
    }
    for (; i < end; ++i) {
        int2 p = csr[i];
        acc += fmaxf(__builtin_nontemporal_load(eattr + p.y * 16 + lane)
                     + feat[p.x * 16 + lane], 0.0f);
    }
    aggr[n * 16 + lane] = acc;
}

// ---------------------------------------------------------------------------
// Node MLP layer 1: h = relu( relu((x+aggr)@W1a + b1a) @ W1b + b1b )
// ---------------------------------------------------------------------------
__global__ __launch_bounds__(256) void node1_kernel(
    const float* __restrict__ x, const float* __restrict__ aggr,
    const float* __restrict__ W1a, const float* __restrict__ b1a,
    const float* __restrict__ W1b, const float* __restrict__ b1b,
    float* __restrict__ h)
{
    __shared__ float sWa[256], sWb[256], sba[16], sbb[16];
    int t = threadIdx.x;
    if (t < 256) { sWa[t] = W1a[t]; sWb[t] = W1b[t]; }
    if (t < 16)  { sba[t] = b1a[t]; sbb[t] = b1b[t]; }
    __syncthreads();

    int n = blockIdx.x * blockDim.x + t;
    if (n >= N_NODES) return;

    float v[16];
#pragma unroll
    for (int i = 0; i < 16; ++i) v[i] = x[n * 16 + i] + aggr[n * 16 + i];

    float u[16];
#pragma unroll
    for (int j = 0; j < 16; ++j) {
        float s = sba[j];
#pragma unroll
        for (int i = 0; i < 16; ++i) s += v[i] * sWa[i * 16 + j];
        u[j] = fmaxf(s, 0.0f);
    }
#pragma unroll
    for (int j = 0; j < 16; ++j) {
        float s = sbb[j];
#pragma unroll
        for (int i = 0; i < 16; ++i) s += u[i] * sWb[i * 16 + j];
        h[n * 16 + j] = fmaxf(s, 0.0f);   // outer relu between layers
    }
}

// ---------------------------------------------------------------------------
// Node MLP layer 2 + pooling accumulation
// ---------------------------------------------------------------------------
__global__ __launch_bounds__(256) void node2_kernel(
    const float* __restrict__ h, const float* __restrict__ aggr,
    const int* __restrict__ batch,
    const float* __restrict__ W2a, const float* __restrict__ b2a,
    const float* __restrict__ W2b, const float* __restrict__ b2b,
    float* __restrict__ sums, float* __restrict__ counts)
{
    __shared__ float sWa[16 * 6], sWb[6 * 6], sba[6], sbb[6];
    int t = threadIdx.x;
    if (t < 96) sWa[t] = W2a[t];
    if (t < 36) sWb[t] = W2b[t];
    if (t < 6)  { sba[t] = b2a[t]; sbb[t] = b2b[t]; }
    __syncthreads();

    int n = blockIdx.x * blockDim.x + t;
    if (n >= N_NODES) return;

    float v[16];
#pragma unroll
    for (int i = 0; i < 16; ++i) v[i] = h[n * 16 + i] + aggr[n * 16 + i];

    float u[6];
#pragma unroll
    for (int j = 0; j < 6; ++j) {
        float s = sba[j];
#pragma unroll
        for (int i = 0; i < 16; ++i) s += v[i] * sWa[i * 6 + j];
        u[j] = fmaxf(s, 0.0f);
    }
    int g = batch[n];
#pragma unroll
    for (int j = 0; j < 6; ++j) {
        float s = sbb[j];
#pragma unroll
        for (int i = 0; i < 6; ++i) s += u[i] * sWb[i * 6 + j];
        atomicAdd(&sums[g * 6 + j], s);
    }
    atomicAdd(&counts[g], 1.0f);
}

// ---------------------------------------------------------------------------
// Pool + log_softmax
// ---------------------------------------------------------------------------
__global__ __launch_bounds__(256) void pool_kernel(
    const float* __restrict__ sums, const float* __restrict__ counts,
    float* __restrict__ out)
{
    int g = blockIdx.x * blockDim.x + threadIdx.x;
    if (g >= N_GRAPHS) return;
    float c = fmaxf(counts[g], 1.0f);
    float p[6];
    float mx = -INFINITY;
#pragma unroll
    for (int j = 0; j < 6; ++j) {
        p[j] = sums[g * 6 + j] / c;
        mx = fmaxf(mx, p[j]);
    }
    float se = 0.0f;
#pragma unroll
    for (int j = 0; j < 6; ++j) se += expf(p[j] - mx);
    float lse = mx + logf(se);
#pragma unroll
    for (int j = 0; j < 6; ++j) out[g * 6 + j] = p[j] - lse;
}

// ---------------------------------------------------------------------------
extern "C" void kernel_launch(void* const* d_in, const int* in_sizes, int n_in,
                              void* d_out, int out_size, void* d_ws, size_t ws_size,
                              hipStream_t stream)
{
    const float* x     = (const float*)d_in[0];
    const int*   ei    = (const int*)  d_in[1];   // [2, E] int32
    const float* eattr = (const float*)d_in[2];
    const int*   batch = (const int*)  d_in[3];
    const float* W1a = (const float*)d_in[4];
    const float* b1a = (const float*)d_in[5];
    const float* W1b = (const float*)d_in[6];
    const float* b1b = (const float*)d_in[7];
    const float* W2a = (const float*)d_in[8];
    const float* b2a = (const float*)d_in[9];
    const float* W2b = (const float*)d_in[10];
    const float* b2b = (const float*)d_in[11];
    float* out = (float*)d_out;

    // ---- workspace layout (~103.5 MB) ----
    // csr [E] int2                : 51.2 MB
    // tmp [E] int2                : 51.2 MB  (dead after K4; aggr+h overlay it)
    // gcnt/base/cursor/offs/sums/counts : ~0.5 MB
    int2* csr    = (int2*)d_ws;
    int2* tmp    = csr + (size_t)N_EDGES;
    float* aggr  = (float*)tmp;                       // overlays tmp after K4
    float* h     = aggr + (size_t)N_NODES * 16;
    int*  gcnt   = (int*)(tmp + (size_t)N_EDGES);
    int*  base   = gcnt + NBUCK;                      // [NBUCK+1]
    int*  cursor = base + NBUCK + 1;                  // [NBUCK]
    int*  offs   = cursor + NBUCK;                    // [N_NODES+1]
    float* sums  = (float*)(offs + N_NODES + 1);      // [G,6]
    float* counts= sums + (size_t)N_GRAPHS * 6;       // [G]

    const int TB = 256;
    const int node_blocks = (N_NODES + TB - 1) / TB;
    const int gather_blocks = (N_NODES + 15) / 16;

    // ---- CSR build via two-level bucket sort ----
    hipMemsetAsync(gcnt, 0, (size_t)NBUCK * sizeof(int), stream);
    count_buckets<<<KBLOCKS, 1024, 0, stream>>>(ei, gcnt);
    scan_buckets<<<1, 1024, 0, stream>>>(gcnt, base, cursor, offs);
    scatter_buckets<<<KBLOCKS, 1024, 0, stream>>>(ei, cursor, tmp);
    bucket_place<<<NBUCK, 1024, 0, stream>>>(base, tmp, csr, offs);

    // ---- layer 1 ----
    gather_kernel<<<gather_blocks, TB, 0, stream>>>(offs, csr, x, eattr, aggr);
    node1_kernel<<<node_blocks, TB, 0, stream>>>(x, aggr, W1a, b1a, W1b, b1b, h);

    // ---- layer 2 ----
    gather_kernel<<<gather_blocks, TB, 0, stream>>>(offs, csr, h, eattr, aggr);
    hipMemsetAsync(sums, 0, (size_t)(N_GRAPHS * 6 + N_GRAPHS) * sizeof(float), stream);
    node2_kernel<<<node_blocks, TB, 0, stream>>>(h, aggr, batch, W2a, b2a, W2b, b2b,
                                                 sums, counts);

    // ---- pool + log_softmax ----
    pool_kernel<<<(N_GRAPHS + TB - 1) / TB, TB, 0, stream>>>(sums, counts, out);
}